// Round 11
// baseline (408.136 us; speedup 1.0000x reference)
//
#include <hip/hip_runtime.h>
#include <hip/hip_bf16.h>
#include <math.h>

#define DEV __device__ __forceinline__

constexpr int Bb   = 32;
constexpr int Nn   = 128;
constexpr int Ff   = 10;
constexpr int Dd   = 64;
constexpr int TOPK = 20;
constexpr int EXTRA= 25;
constexpr int BN   = 4096;   // B*N
constexpr int TBN  = 8192;   // 2*BN
constexpr int RC   = 32;     // r-chunks for split-K ef
constexpr int CAP16 = 2048;  // pivot-bin candidate cap (radix16)
constexpr int TCAP  = 256;   // boundary-tie cap
constexpr float EPS   = 1e-5f;
constexpr float SLOPE = 0.2f;

// order-preserving float<->uint encoding (monotone: a<b  <=> fenc(a)<fenc(b))
DEV unsigned int fenc(float f){
  unsigned int b = __float_as_uint(f);
  return (b & 0x80000000u) ? ~b : (b | 0x80000000u);
}
DEV float fdec(unsigned int u){
  unsigned int b = (u & 0x80000000u) ? (u & 0x7FFFFFFFu) : ~u;
  return __uint_as_float(b);
}

// ---------------- generic zero ----------------
__global__ void k_zero(float* __restrict__ p, int n){
  int i = blockIdx.x*256 + threadIdx.x;
  if(i < n) p[i] = 0.f;
}

// ---------------- emb row norms ----------------
__global__ void k_emb_norm(const float* __restrict__ emb, float* __restrict__ norms){
  int i = blockIdx.x, d = threadIdx.x;
  float v = emb[i*Dd + d];
  float s = v*v;
  for(int o=32;o>0;o>>=1) s += __shfl_down(s, o, 64);
  if(d==0) norms[i] = fmaxf(sqrtf(s), 1e-12f);
}

// ---------------- emb cosine + top-20 per row ----------------
__global__ void k_emb_topk(const float* __restrict__ emb, const float* __restrict__ norms,
                           float* __restrict__ topv, int* __restrict__ topi){
  __shared__ float se[Dd];
  __shared__ float sc[Nn];
  __shared__ float rv[Nn];
  __shared__ int   ri[Nn];
  int i = blockIdx.x, t = threadIdx.x;
  if(t < Dd) se[t] = emb[i*Dd + t];
  __syncthreads();
  float dot = 0.f;
  for(int d=0; d<Dd; d++) dot += se[d]*emb[t*Dd + d];
  sc[t] = dot/(norms[i]*norms[t]);
  __syncthreads();
  for(int k=0; k<TOPK; k++){
    rv[t] = sc[t]; ri[t] = t; __syncthreads();
    for(int o=Nn/2; o>0; o>>=1){
      if(t < o){
        float v2 = rv[t+o]; int i2 = ri[t+o];
        if(v2 > rv[t] || (v2 == rv[t] && i2 < ri[t])){ rv[t]=v2; ri[t]=i2; }
      }
      __syncthreads();
    }
    if(t==0){
      topv[i*TOPK + k] = rv[0];
      topi[i*TOPK + k] = ri[0];
      sc[ri[0]] = -INFINITY;
    }
    __syncthreads();
  }
}

// ---------------- h = x@W1, si/sj attention logits ----------------
__global__ void k_h1(const float* __restrict__ data, const float* __restrict__ emb,
                     const float* __restrict__ W1, const float* __restrict__ ai1,
                     const float* __restrict__ aj1,
                     float* __restrict__ h, float* __restrict__ si, float* __restrict__ sj){
  int r = blockIdx.x, d = threadIdx.x;
  int node = r & (Nn-1);
  __shared__ float xr[Ff];
  if(d < Ff) xr[d] = data[r*Ff + d];
  __syncthreads();
  float hv = 0.f;
  #pragma unroll
  for(int f=0; f<Ff; f++) hv += xr[f]*W1[f*Dd + d];
  h[r*Dd + d] = hv;
  float e = emb[node*Dd + d];
  float a = hv*ai1[d] + e*ai1[Dd + d];
  float b = hv*aj1[d] + e*aj1[Dd + d];
  for(int o=32;o>0;o>>=1){ a += __shfl_down(a,o,64); b += __shfl_down(b,o,64); }
  if(d==0){ si[r] = a; sj[r] = b; }
}

// ---------------- layer-1 segment softmax + aggregation ----------------
__global__ void k_agg1(const float* __restrict__ h, const float* __restrict__ si,
                       const float* __restrict__ sj, const float* __restrict__ topv,
                       const int* __restrict__ topi, const float* __restrict__ bias1,
                       float* __restrict__ agg){
  int r = blockIdx.x, d = threadIdx.x;
  int b = r >> 7, node = r & (Nn-1);
  __shared__ float sal[TOPK];
  __shared__ int   ssrc[TOPK];
  if(d < TOPK){
    int s = b*Nn + topi[node*TOPK + d];
    float sc = si[r] + sj[s];
    sc = sc >= 0.f ? sc : SLOPE*sc;
    sal[d] = sc * topv[node*TOPK + d];
    ssrc[d] = s;
  }
  __syncthreads();
  float m = -INFINITY;
  #pragma unroll
  for(int k=0;k<TOPK;k++) m = fmaxf(m, sal[k]);
  float al[TOPK]; float ssum = 0.f;
  #pragma unroll
  for(int k=0;k<TOPK;k++){ al[k] = expf(sal[k]-m); ssum += al[k]; }
  float inv = 1.0f/fmaxf(ssum, 1e-12f);
  float acc = 0.f;
  #pragma unroll
  for(int k=0;k<TOPK;k++) acc += al[k]*inv*h[ssrc[k]*Dd + d];
  agg[r*Dd + d] = acc + bias1[d];
}

// ---------------- per-channel stats over BN rows (agg1) ----------------
__global__ void k_colstats(const float* __restrict__ x, float* __restrict__ mu, float* __restrict__ var){
  int c = blockIdx.x, t = threadIdx.x;
  float s = 0.f, s2 = 0.f;
  for(int r=t; r<BN; r+=256){ float v = x[r*Dd + c]; s += v; s2 += v*v; }
  __shared__ float ls[256], ls2[256];
  ls[t]=s; ls2[t]=s2; __syncthreads();
  for(int o=128;o>0;o>>=1){
    if(t<o){ ls[t]+=ls[t+o]; ls2[t]+=ls2[t+o]; }
    __syncthreads();
  }
  if(t==0){ float m = ls[0]/BN; mu[c]=m; var[c]=ls2[0]/BN - m*m; }
}

// ---------------- BN1 + relu -> g[0:BN] ----------------
__global__ void k_bnrelu1(const float* __restrict__ agg, const float* __restrict__ mu,
                          const float* __restrict__ var, const float* __restrict__ gamma,
                          const float* __restrict__ beta, float* __restrict__ g){
  int idx = blockIdx.x*256 + threadIdx.x;
  int c = idx & (Dd-1);
  float v = agg[idx];
  float y = gamma[c]*(v - mu[c])/sqrtf(var[c]+EPS) + beta[c];
  g[idx] = fmaxf(y, 0.f);
}

// ---------------- ef stage 1: partial P^T @ gcn tiles, non-atomic ----------------
__global__ __launch_bounds__(256) void k_ef1(const float* __restrict__ P, const float* __restrict__ gcn,
                                             float* __restrict__ part){
  __shared__ float Pt[16*64];
  __shared__ float Gt[16*64];
  int t = threadIdx.x;
  int jbase = blockIdx.x*64;
  int r0 = blockIdx.y*128;
  int row = t >> 4, col4 = (t & 15)*4;
  int tr = t >> 4, tc = t & 15;
  float acc[4][4] = {};
  for(int step=0; step<8; step++){
    int r = r0 + step*16;
    float4 pv = *(const float4*)&P[(size_t)(r+row)*BN + jbase + col4];
    float4 gv = *(const float4*)&gcn[(r+row)*Dd + col4];
    __syncthreads();
    *(float4*)&Pt[row*64 + col4] = pv;
    *(float4*)&Gt[row*64 + col4] = gv;
    __syncthreads();
    #pragma unroll
    for(int rr=0; rr<16; rr++){
      float4 pa = *(float4*)&Pt[rr*64 + tr*4];
      float4 gb = *(float4*)&Gt[rr*64 + tc*4];
      float pav[4] = {pa.x, pa.y, pa.z, pa.w};
      float gbv[4] = {gb.x, gb.y, gb.z, gb.w};
      #pragma unroll
      for(int a=0;a<4;a++)
        #pragma unroll
        for(int b=0;b<4;b++) acc[a][b] += pav[a]*gbv[b];
    }
  }
  float* dst = part + ((size_t)blockIdx.y*BN + jbase)*Dd;
  #pragma unroll
  for(int a=0;a<4;a++){
    float4 v = make_float4(acc[a][0],acc[a][1],acc[a][2],acc[a][3]);
    *(float4*)&dst[(tr*4+a)*Dd + tc*4] = v;
  }
}

// ---------------- ef stage 2: reduce RC partials ----------------
__global__ void k_ef2(const float* __restrict__ part, float* __restrict__ ef){
  int i = blockIdx.x*256 + threadIdx.x;
  float4 s = make_float4(0.f,0.f,0.f,0.f);
  #pragma unroll
  for(int c=0;c<RC;c++){
    float4 v = *(const float4*)&part[(size_t)c*BN*Dd + (size_t)i*4];
    s.x += v.x; s.y += v.y; s.z += v.z; s.w += v.w;
  }
  *(float4*)&ef[(size_t)i*4] = s;
}

// ---------------- row norms of g (8192 rows) ----------------
__global__ void k_rownorm(const float* __restrict__ x, float* __restrict__ nrm){
  int r = blockIdx.x, d = threadIdx.x;
  float v = x[(size_t)r*Dd + d];
  float s = v*v;
  for(int o=32;o>0;o>>=1) s += __shfl_down(s, o, 64);
  if(d==0) nrm[r] = fmaxf(sqrtf(s), 1e-12f);
}

// ---------------- S chunk GEMM -> 16-bit codes: S16[r][c] = fenc(cos)>>16 ----------------
__global__ __launch_bounds__(256) void k_sgemm16(const float* __restrict__ g, const float* __restrict__ gnorm,
                                                 int rbase, unsigned short* __restrict__ S16){
  __shared__ float A[64*128];
  __shared__ float Bs[64*128];
  int t = threadIdx.x;
  int ctile = blockIdx.x*128;
  int rtile = rbase + blockIdx.y*128;
  int q = t >> 4, m0 = t & 15;
  #pragma unroll
  for(int l=0;l<8;l++){
    int m = m0 + 16*l;
    float ia = 1.0f/gnorm[rtile + m];
    float ib = 1.0f/gnorm[ctile + m];
    float4 av = *(const float4*)&g[(size_t)(rtile+m)*Dd + q*4];
    float4 bv = *(const float4*)&g[(size_t)(ctile+m)*Dd + q*4];
    A[(q*4+0)*128 + m] = av.x*ia; A[(q*4+1)*128 + m] = av.y*ia;
    A[(q*4+2)*128 + m] = av.z*ia; A[(q*4+3)*128 + m] = av.w*ia;
    Bs[(q*4+0)*128 + m] = bv.x*ib; Bs[(q*4+1)*128 + m] = bv.y*ib;
    Bs[(q*4+2)*128 + m] = bv.z*ib; Bs[(q*4+3)*128 + m] = bv.w*ib;
  }
  __syncthreads();
  int tr = t >> 4;
  int tc = t & 15;
  float acc[8][8] = {};
  #pragma unroll 4
  for(int k=0;k<64;k++){
    float a[8], b[8];
    #pragma unroll
    for(int i=0;i<8;i++) a[i] = A[k*128 + tr + 16*i];
    #pragma unroll
    for(int j=0;j<8;j++) b[j] = Bs[k*128 + tc + 16*j];
    #pragma unroll
    for(int i=0;i<8;i++)
      #pragma unroll
      for(int j=0;j<8;j++) acc[i][j] += a[i]*b[j];
  }
  int rloc = blockIdx.y*128;
  #pragma unroll
  for(int i=0;i<8;i++){
    int r = rloc + tr + 16*i;
    #pragma unroll
    for(int j=0;j<8;j++)
      S16[(size_t)r*TBN + ctile + tc + 16*j] = (unsigned short)(fenc(acc[i][j]) >> 16);
  }
}

// ---------------- top-25 select on 16-bit codes ----------------
// 12-bit histogram on code bits[15:4] -> pivot bin; within bin, 16-bit rank
// decides sure members; boundary tie group (equal code16 at rank 25) deferred
// to k_gather for exact refinement. Overflow -> flag (full-row fallback).
__global__ __launch_bounds__(256) void k_radix16(const unsigned short* __restrict__ S16, int rbase,
                                                 int4* __restrict__ hdr, int* __restrict__ selcols,
                                                 int* __restrict__ tiecols){
  __shared__ unsigned hist[4096];
  __shared__ unsigned wtot[4];
  __shared__ unsigned cand[CAP16];   // (code16<<13)|col
  __shared__ unsigned bc_bin, bc_need, bc_sure, bc_c, bc_tie, bc_n3;
  int t = threadIdx.x;
  int lane = t & 63, wid = t >> 6;
  int r = blockIdx.x;
  const uint4* src = (const uint4*)(S16 + (size_t)r*TBN);
  unsigned code[32];
  #pragma unroll
  for(int j=0;j<4;j++){
    uint4 u = src[t*4 + j];
    code[j*8+0]=u.x&0xFFFFu; code[j*8+1]=u.x>>16;
    code[j*8+2]=u.y&0xFFFFu; code[j*8+3]=u.y>>16;
    code[j*8+4]=u.z&0xFFFFu; code[j*8+5]=u.z>>16;
    code[j*8+6]=u.w&0xFFFFu; code[j*8+7]=u.w>>16;
  }
  #pragma unroll
  for(int j=0;j<16;j++) hist[t*16 + j] = 0u;
  __syncthreads();
  #pragma unroll
  for(int j=0;j<32;j++) atomicAdd(&hist[code[j] >> 4], 1u);
  __syncthreads();
  unsigned lsum = 0u;
  #pragma unroll
  for(int j=0;j<16;j++) lsum += hist[t*16 + j];
  unsigned v = lsum;
  #pragma unroll
  for(int o=1;o<64;o<<=1){
    unsigned u = (unsigned)__shfl_down((int)v, o, 64);
    if(lane + o < 64) v += u;
  }
  if(lane == 0) wtot[wid] = v;
  __syncthreads();
  unsigned cross = 0u;
  #pragma unroll
  for(int w2=0;w2<4;w2++) if(w2 > wid) cross += wtot[w2];
  unsigned Tinc = v + cross;
  unsigned above = Tinc - lsum;
  unsigned run = above;
  #pragma unroll
  for(int b=15;b>=0;b--){
    unsigned prev = run;
    run += hist[t*16 + b];
    if(run >= EXTRA && prev < EXTRA){ bc_bin = (unsigned)(t*16 + b); bc_need = EXTRA - prev; }
  }
  if(t==0){ bc_sure = 0u; bc_c = 0u; bc_tie = 0u; bc_n3 = 0u; }
  __syncthreads();
  unsigned pivotBin = bc_bin, needIn = bc_need;
  int gr = rbase + r;
  int col0 = t*32;
  #pragma unroll
  for(int j=0;j<32;j++){
    unsigned cd = code[j];
    unsigned bin = cd >> 4;
    if(bin > pivotBin){
      unsigned s = atomicAdd(&bc_sure, 1u);
      selcols[gr*32 + s] = col0 + j;
    } else if(bin == pivotBin){
      unsigned ci = atomicAdd(&bc_c, 1u);
      if(ci < CAP16) cand[ci] = (cd << 13) | (unsigned)(col0 + j);
    }
  }
  __syncthreads();
  unsigned c = bc_c;
  int flag = (c > CAP16) ? 1 : 0;
  if(!flag){
    for(unsigned i=t; i<c; i+=256){
      unsigned pk = cand[i];
      unsigned myc = pk >> 13;
      unsigned gt = 0, eq = 0;
      for(unsigned j2=0;j2<c;j2++){
        unsigned oc = cand[j2] >> 13;
        gt += (oc > myc); eq += (oc == myc);
      }
      if(gt + eq <= needIn){
        unsigned s = atomicAdd(&bc_sure, 1u);
        selcols[gr*32 + s] = (int)(pk & 8191u);
      } else if(gt < needIn){
        unsigned u = atomicAdd(&bc_tie, 1u);
        if(u < TCAP) tiecols[gr*TCAP + u] = (int)(pk & 8191u);
        bc_n3 = needIn - gt;   // same value for all boundary members
      }
    }
  }
  __syncthreads();
  if(bc_tie > TCAP) flag = 1;
  if(t==0) hdr[gr] = make_int4((int)bc_sure, (int)(bc_tie > TCAP ? TCAP : bc_tie), (int)bc_n3, flag);
}

// ---------------- gather: exact values for selections + tie refinement ----------------
__global__ __launch_bounds__(64) void k_gather(const float* __restrict__ g, const float* __restrict__ gnorm,
                                               const int4* __restrict__ hdr, const int* __restrict__ selcols,
                                               const int* __restrict__ tiecols,
                                               float* __restrict__ topv2, int* __restrict__ topi2){
  __shared__ float ar[64];
  __shared__ float rowv[TBN];
  __shared__ unsigned tE[TCAP];
  __shared__ int scnt;
  int r = blockIdx.x, t = threadIdx.x;
  int4 H = hdr[r];
  float invr = 1.0f/gnorm[r];
  ar[t] = g[(size_t)r*Dd + t]*invr;
  if(t==0) scnt = 0;
  __syncthreads();
  // mirrors k_sgemm16 arithmetic: mul-normalize both, ascending-k fma chain
  auto dotc = [&](int c)->float{
    float invc = 1.0f/gnorm[c];
    float acc = 0.f;
    const float* gc = g + (size_t)c*Dd;
    for(int k=0;k<Dd;k++) acc = fmaf(ar[k], gc[k]*invc, acc);
    return acc;
  };
  if(!H.w){
    int sc = H.x, tcnt = H.y, need3 = H.z;
    for(int i=t; i<sc; i+=64){
      int c = selcols[r*32 + i];
      topv2[r*EXTRA + i] = dotc(c);
      topi2[r*EXTRA + i] = c;
    }
    for(int i=t; i<tcnt; i+=64) tE[i] = fenc(dotc(tiecols[r*TCAP + i]));
    __syncthreads();
    for(int i=t; i<tcnt; i+=64){
      unsigned e = tE[i]; int c = tiecols[r*TCAP + i];
      int rank = 0;
      for(int j=0;j<tcnt;j++){
        unsigned e2 = tE[j]; int c2 = tiecols[r*TCAP + j];
        rank += (e2 > e) || (e2 == e && c2 < c);
      }
      if(rank < need3){
        int s = sc + atomicAdd(&scnt, 1);
        topv2[r*EXTRA + s] = fdec(e);
        topi2[r*EXTRA + s] = c;
      }
    }
  } else {
    // rare exact fallback: recompute full row, 25 argmax pops
    for(int c=t; c<TBN; c+=64) rowv[c] = dotc(c);
    __syncthreads();
    float bv = -INFINITY; int bc = 0x7FFFFFFF;
    for(int j=0;j<128;j++){
      int c = j*64 + t; float vv = rowv[c];
      if(vv > bv || (vv == bv && c < bc)){ bv = vv; bc = c; }
    }
    for(int k=0;k<EXTRA;k++){
      float gv = bv; int gi = bc;
      #pragma unroll
      for(int o=1;o<64;o<<=1){
        float v2 = __shfl_xor(gv, o, 64); int i2 = __shfl_xor(gi, o, 64);
        if(v2 > gv || (v2 == gv && i2 < gi)){ gv = v2; gi = i2; }
      }
      if(t==0){ topv2[r*EXTRA + k] = gv; topi2[r*EXTRA + k] = gi; }
      int owner = gi & 63;
      if(t == owner){
        rowv[gi] = -INFINITY;
        bv = -INFINITY; bc = 0x7FFFFFFF;
        for(int j=0;j<128;j++){
          int c = j*64 + t; float vv = rowv[c];
          if(vv > bv || (vv == bv && c < bc)){ bv = vv; bc = c; }
        }
      }
    }
  }
}

// ---------------- h2 = g@W2 (rows < BN only), attention logits ----------------
__global__ void k_h2(const float* __restrict__ g, const float* __restrict__ W2,
                     const float* __restrict__ ai2w, const float* __restrict__ aj2w,
                     float* __restrict__ h2, float* __restrict__ a2i, float* __restrict__ a2j){
  int r = blockIdx.x, d = threadIdx.x;
  __shared__ float gr[Dd];
  gr[d] = g[(size_t)r*Dd + d];
  __syncthreads();
  float hv = 0.f;
  #pragma unroll
  for(int k=0;k<Dd;k++) hv += gr[k]*W2[k*Dd + d];
  h2[(size_t)r*Dd + d] = hv;
  float a = hv*ai2w[d];
  float b = hv*aj2w[d];
  for(int o=32;o>0;o>>=1){ a += __shfl_down(a,o,64); b += __shfl_down(b,o,64); }
  if(d==0){ a2i[r]=a; a2j[r]=b; }
}

// ---------------- layer-2 edge scores + segment max (dst<BN only) ----------------
__global__ void k_s2(const float* __restrict__ a2i, const float* __restrict__ a2j,
                     const float* __restrict__ topv2, const int* __restrict__ topi2,
                     float* __restrict__ s2, unsigned int* __restrict__ segmax){
  int e = blockIdx.x*256 + threadIdx.x;
  if(e >= BN*EXTRA) return;
  int dst = topi2[e];
  if(dst >= BN) return;           // dead edge: agg2 rows >= BN are discarded
  int r = e/EXTRA;
  float sc = a2i[dst] + a2j[r];
  sc = sc >= 0.f ? sc : SLOPE*sc;
  sc *= topv2[e];
  s2[e] = sc;
  atomicMax(&segmax[dst], fenc(sc));
}

// ---------------- exp + segment sum (dst<BN only) ----------------
__global__ void k_e2(const float* __restrict__ s2, const int* __restrict__ topi2,
                     const unsigned int* __restrict__ segmax,
                     float* __restrict__ e2, float* __restrict__ ssum){
  int e = blockIdx.x*256 + threadIdx.x;
  if(e >= BN*EXTRA) return;
  int dst = topi2[e];
  if(dst >= BN) return;
  float m = fdec(segmax[dst]);
  float v = expf(s2[e] - m);
  e2[e] = v;
  atomicAdd(&ssum[dst], v);
}

// ---------------- weighted scatter into agg2 (dst<BN only) ----------------
__global__ void k_scat(const float* __restrict__ e2, const float* __restrict__ ssum,
                       const int* __restrict__ topi2, const float* __restrict__ h2,
                       float* __restrict__ agg2){
  int idx = blockIdx.x*256 + threadIdx.x;
  int e = idx >> 6, d = idx & 63;
  int dst = topi2[e];
  if(dst >= BN) return;
  int src = e/EXTRA;
  float alpha = e2[e]/fmaxf(ssum[dst], 1e-12f);
  atomicAdd(&agg2[(size_t)dst*Dd + d], alpha*h2[(size_t)src*Dd + d]);
}

// ---------------- head stats over x3 = relu(agg2+bias2)*emb ----------------
__global__ void k_headstats(const float* __restrict__ agg2, const float* __restrict__ bias2,
                            const float* __restrict__ emb, float* __restrict__ mu2, float* __restrict__ var2){
  int c = blockIdx.x, t = threadIdx.x;
  float bc = bias2[c];
  float s = 0.f, s2 = 0.f;
  for(int r=t; r<BN; r+=256){
    float v = fmaxf(agg2[(size_t)r*Dd + c] + bc, 0.f) * emb[(r & (Nn-1))*Dd + c];
    s += v; s2 += v*v;
  }
  __shared__ float ls[256], ls2[256];
  ls[t]=s; ls2[t]=s2; __syncthreads();
  for(int o=128;o>0;o>>=1){
    if(t<o){ ls[t]+=ls[t+o]; ls2[t]+=ls2[t+o]; }
    __syncthreads();
  }
  if(t==0){ float m=ls[0]/BN; mu2[c]=m; var2[c]=ls2[0]/BN - m*m; }
}

// ---------------- final: BN + relu + Linear(D,1) ----------------
__global__ void k_out(const float* __restrict__ agg2, const float* __restrict__ bias2,
                      const float* __restrict__ emb, const float* __restrict__ mu2,
                      const float* __restrict__ var2, const float* __restrict__ gO,
                      const float* __restrict__ bO, const float* __restrict__ Wout,
                      const float* __restrict__ bout, float* __restrict__ out){
  int r = blockIdx.x, d = threadIdx.x;
  float v = fmaxf(agg2[(size_t)r*Dd + d] + bias2[d], 0.f) * emb[(r & (Nn-1))*Dd + d];
  float y = gO[d]*(v - mu2[d])/sqrtf(var2[d]+EPS) + bO[d];
  y = fmaxf(y, 0.f)*Wout[d];
  for(int o=32;o>0;o>>=1) y += __shfl_down(y, o, 64);
  if(d==0) out[r] = y + bout[0];
}

extern "C" void kernel_launch(void* const* d_in, const int* in_sizes, int n_in,
                              void* d_out, int out_size, void* d_ws, size_t ws_size,
                              hipStream_t stream){
  const float* data  = (const float*)d_in[0];
  const float* emb   = (const float*)d_in[1];
  const float* W1    = (const float*)d_in[2];
  const float* ai1   = (const float*)d_in[3];
  const float* aj1   = (const float*)d_in[4];
  const float* bias1 = (const float*)d_in[5];
  const float* bn1g  = (const float*)d_in[6];
  const float* bn1b  = (const float*)d_in[7];
  const float* P     = (const float*)d_in[8];
  const float* W2    = (const float*)d_in[9];
  const float* ai2w  = (const float*)d_in[10];
  const float* aj2w  = (const float*)d_in[11];
  const float* bias2 = (const float*)d_in[12];
  const float* bnOg  = (const float*)d_in[13];
  const float* bnOb  = (const float*)d_in[14];
  const float* Wout  = (const float*)d_in[15];
  const float* bout  = (const float*)d_in[16];
  float* out = (float*)d_out;

  char* w = (char*)d_ws;
  auto alloc = [&](size_t nbytes)->char*{
    char* p = w; w += (nbytes + 255) & ~(size_t)255; return p;
  };
  float* norms1 = (float*)alloc(Nn*4);
  float* topv1  = (float*)alloc(Nn*TOPK*4);
  int*   topi1  = (int*)  alloc(Nn*TOPK*4);
  float* h      = (float*)alloc((size_t)BN*Dd*4);
  float* si     = (float*)alloc(BN*4);
  float* sj     = (float*)alloc(BN*4);
  float* agg1   = (float*)alloc((size_t)BN*Dd*4);
  float* mu1    = (float*)alloc(Dd*4);
  float* var1   = (float*)alloc(Dd*4);
  float* g      = (float*)alloc((size_t)TBN*Dd*4);
  float* gnorm  = (float*)alloc(TBN*4);
  float* topv2  = (float*)alloc((size_t)BN*EXTRA*4);
  int*   topi2  = (int*)  alloc((size_t)BN*EXTRA*4);
  int4*  hdr    = (int4*) alloc((size_t)BN*16);
  int*   selcols= (int*)  alloc((size_t)BN*32*4);
  int*   tiecols= (int*)  alloc((size_t)BN*TCAP*4);
  float* h2     = (float*)alloc((size_t)BN*Dd*4);
  float* a2i    = (float*)alloc(BN*4);
  float* a2j    = (float*)alloc(BN*4);
  float* s2     = (float*)alloc((size_t)BN*EXTRA*4);
  float* e2     = (float*)alloc((size_t)BN*EXTRA*4);
  // contiguous zero region: agg2 | ssum | segmax (BN rows only)
  float* zblock = (float*)alloc(((size_t)BN*Dd + BN + BN)*4);
  float* agg2   = zblock;
  float* ssum   = zblock + (size_t)BN*Dd;
  unsigned int* segmax = (unsigned int*)(ssum + BN);
  float* mu2    = (float*)alloc(Dd*4);
  float* var2   = (float*)alloc(Dd*4);
  float* efpart = (float*)alloc((size_t)RC*BN*Dd*4);   // 32 MB split-K partials

  // adaptive S16 chunk (ushort codes; multiple of 128 rows)
  size_t used = (size_t)(w - (char*)d_ws);
  size_t rem  = ws_size > used ? ws_size - used : 0;
  int chunkRows = 4096;
  while(chunkRows > 128 && (size_t)chunkRows*TBN*2 > rem) chunkRows >>= 1;
  unsigned short* S16 = (unsigned short*)alloc((size_t)chunkRows*TBN*2);

  // ---- layer 1 ----
  k_emb_norm<<<Nn, 64, 0, stream>>>(emb, norms1);
  k_emb_topk<<<Nn, Nn, 0, stream>>>(emb, norms1, topv1, topi1);
  k_h1<<<BN, 64, 0, stream>>>(data, emb, W1, ai1, aj1, h, si, sj);
  k_agg1<<<BN, 64, 0, stream>>>(h, si, sj, topv1, topi1, bias1, agg1);
  k_colstats<<<Dd, 256, 0, stream>>>(agg1, mu1, var1);
  k_bnrelu1<<<(BN*Dd)/256, 256, 0, stream>>>(agg1, mu1, var1, bn1g, bn1b, g);

  // ---- ef = P^T gcn : split-K, no atomics ----
  k_ef1<<<dim3(64, RC), 256, 0, stream>>>(P, g, efpart);
  k_ef2<<<(BN*Dd/4)/256, 256, 0, stream>>>(efpart, g + (size_t)BN*Dd);

  // ---- cos2 top-25: 16-bit-code GEMM + select + exact gather ----
  k_rownorm<<<TBN, 64, 0, stream>>>(g, gnorm);
  for(int rbase=0; rbase<BN; rbase+=chunkRows){
    k_sgemm16<<<dim3(TBN/128, chunkRows/128), 256, 0, stream>>>(g, gnorm, rbase, S16);
    k_radix16<<<chunkRows, 256, 0, stream>>>(S16, rbase, hdr, selcols, tiecols);
  }
  k_gather<<<BN, 64, 0, stream>>>(g, gnorm, hdr, selcols, tiecols, topv2, topi2);

  // ---- layer 2 (dead edges dst>=BN eliminated) ----
  k_h2<<<BN, 64, 0, stream>>>(g, W2, ai2w, aj2w, h2, a2i, a2j);
  k_zero<<<((BN*Dd + 2*BN) + 255)/256, 256, 0, stream>>>(zblock, BN*Dd + 2*BN);
  k_s2<<<(BN*EXTRA + 255)/256, 256, 0, stream>>>(a2i, a2j, topv2, topi2, s2, segmax);
  k_e2<<<(BN*EXTRA + 255)/256, 256, 0, stream>>>(s2, topi2, segmax, e2, ssum);
  k_scat<<<(BN*EXTRA*Dd)/256, 256, 0, stream>>>(e2, ssum, topi2, h2, agg2);

  // ---- head ----
  k_headstats<<<Dd, 256, 0, stream>>>(agg2, bias2, emb, mu2, var2);
  k_out<<<BN, 64, 0, stream>>>(agg2, bias2, emb, mu2, var2, bnOg, bnOb, Wout, bout, out);
}